// Round 3
// baseline (392.580 us; speedup 1.0000x reference)
//
#include <hip/hip_runtime.h>
#include <math.h>

#define BN 4
#define DD 256
#define LL 4096
#define NS 16
#define NCH 32   // scan chunks
#define CT 128   // chunk length (NCH*CT == LL)
#define SP 132   // CT + 4 pad

__device__ __forceinline__ float softplus_f(float v) {
  return v > 20.f ? v : log1pf(__expf(v));
}
__device__ __forceinline__ float silu_f(float v) {
  return v / (1.f + __expf(-v));
}

// ---------------- K1: xz = in_proj_w (512x256) @ U[b] (256x4096) ----------------
__global__ __launch_bounds__(256) void k1_inproj(
    const float* __restrict__ W, const float* __restrict__ U,
    float* __restrict__ xpre, float* __restrict__ zb) {
  __shared__ float Wt[16][128];  // [k][e]
  __shared__ float Ut[16][128];  // [k][l]
  const int l0 = blockIdx.x * 128;
  const int e0 = blockIdx.y * 128;
  const int b  = blockIdx.z;
  const int tid = threadIdx.x;
  const int tx = tid & 15, ty = tid >> 4;
  const float* Ub = U + (size_t)b * DD * LL;
  float acc[8][8];
#pragma unroll
  for (int i = 0; i < 8; ++i)
#pragma unroll
    for (int j = 0; j < 8; ++j) acc[i][j] = 0.f;

  for (int k0 = 0; k0 < DD; k0 += 16) {
#pragma unroll
    for (int i = 0; i < 2; ++i) {
      int idx = tid * 8 + i * 4;
      int e = idx >> 4, kk = idx & 15;
      float4 v = *(const float4*)(W + (size_t)(e0 + e) * DD + k0 + kk);
      Wt[kk + 0][e] = v.x; Wt[kk + 1][e] = v.y;
      Wt[kk + 2][e] = v.z; Wt[kk + 3][e] = v.w;
    }
#pragma unroll
    for (int i = 0; i < 2; ++i) {
      int idx = tid * 4 + i * 1024;
      int kk = idx >> 7, l = idx & 127;
      *(float4*)&Ut[kk][l] = *(const float4*)(Ub + (size_t)(k0 + kk) * LL + l0 + l);
    }
    __syncthreads();
#pragma unroll
    for (int kk = 0; kk < 16; ++kk) {
      float a[8], bb2[8];
#pragma unroll
      for (int i = 0; i < 4; ++i) { a[i] = Wt[kk][ty * 4 + i]; a[i + 4] = Wt[kk][64 + ty * 4 + i]; }
#pragma unroll
      for (int j = 0; j < 4; ++j) { bb2[j] = Ut[kk][tx * 4 + j]; bb2[j + 4] = Ut[kk][64 + tx * 4 + j]; }
#pragma unroll
      for (int i = 0; i < 8; ++i)
#pragma unroll
        for (int j = 0; j < 8; ++j) acc[i][j] += a[i] * bb2[j];
    }
    __syncthreads();
  }
#pragma unroll
  for (int i = 0; i < 8; ++i) {
    int e = e0 + ((i < 4) ? (ty * 4 + i) : (64 + ty * 4 + (i - 4)));
    float* dst = (e < DD) ? (xpre + ((size_t)b * DD + e) * LL)
                          : (zb   + ((size_t)b * DD + (e - DD)) * LL);
    float4 v0 = make_float4(acc[i][0], acc[i][1], acc[i][2], acc[i][3]);
    float4 v1 = make_float4(acc[i][4], acc[i][5], acc[i][6], acc[i][7]);
    *(float4*)(dst + l0 + tx * 4) = v0;
    *(float4*)(dst + l0 + 64 + tx * 4) = v1;
  }
}

// ---------------- K3 v2: fused conv + x_proj(GEMM) + dt_proj ----------------
// Block: l-tile of 64 at l0, batch b. Output rows r=0..95: dir=r/48, rr=r%48,
// rr: [0,16)=dt-rank, [16,32)=B, [32,48)=C. Thread tile: 6 rows x 4 cols.
__global__ __launch_bounds__(256) void k3_proj(
    const float* __restrict__ xpre,
    const float* __restrict__ cw, const float* __restrict__ cbg,
    const float* __restrict__ xpw,  const float* __restrict__ dtw,
    const float* __restrict__ dtb,
    const float* __restrict__ xpwB, const float* __restrict__ dtwB,
    float* __restrict__ gdelta, float* __restrict__ gB, float* __restrict__ gC,
    float* __restrict__ xc_out) {
  __shared__ float cwlds[4 * 64];       // w0,w1,w2,bias per l
  __shared__ float wlds[32 * 97];       // [kk][r], stride 97 (conflict-free staging)
  __shared__ float xlds[32 * 68];       // [kk][l], stride 68 (16B aligned)
  __shared__ float dtlds[32 * 68];      // [dir*16+r][l]
  const int l0 = blockIdx.x * 64;
  const int b  = blockIdx.y;
  const int tid = threadIdx.x;
  const int tx = tid & 15, ty = tid >> 4;   // tx: col group of 4, ty: row group of 6

  if (tid < 64) {
    int l = l0 + tid;
    cwlds[tid]       = cw[l * 9 + 3];
    cwlds[64 + tid]  = cw[l * 9 + 4];
    cwlds[128 + tid] = cw[l * 9 + 5];
    cwlds[192 + tid] = cbg[l];
  }
  __syncthreads();

  float acc[6][4];
#pragma unroll
  for (int i = 0; i < 6; ++i)
#pragma unroll
    for (int j = 0; j < 4; ++j) acc[i][j] = 0.f;

  const float* xb = xpre + (size_t)b * DD * LL;

  for (int k0 = 0; k0 < DD; k0 += 32) {
    if (k0) __syncthreads();
    // stage weights: 96 rows x 32 k
    for (int idx = tid; idx < 96 * 32; idx += 256) {
      int r = idx >> 5, kk = idx & 31;
      int dir = r / 48, rr = r - dir * 48;
      const float* Wsrc = dir ? xpwB : xpw;
      wlds[kk * 97 + r] = Wsrc[(size_t)rr * DD + k0 + kk];
    }
    // stage conv(x) chunk: 32 d-rows x 64 l
    for (int idx = tid; idx < 32 * 64; idx += 256) {
      int kk = idx >> 6, l = idx & 63;
      int d = k0 + kk;
      float v = cwlds[192 + l] + cwlds[64 + l] * xb[(size_t)d * LL + l0 + l];
      if (d > 0)   v += cwlds[l]       * xb[(size_t)(d - 1) * LL + l0 + l];
      if (d < 255) v += cwlds[128 + l] * xb[(size_t)(d + 1) * LL + l0 + l];
      xlds[kk * 68 + l] = v;
      xc_out[((size_t)b * DD + d) * LL + l0 + l] = v;
    }
    __syncthreads();
#pragma unroll
    for (int kk = 0; kk < 32; ++kk) {
      float4 x4 = *(float4*)&xlds[kk * 68 + tx * 4];
      float wv[6];
#pragma unroll
      for (int i = 0; i < 6; ++i) wv[i] = wlds[kk * 97 + ty * 6 + i];
#pragma unroll
      for (int i = 0; i < 6; ++i) {
        acc[i][0] += wv[i] * x4.x;
        acc[i][1] += wv[i] * x4.y;
        acc[i][2] += wv[i] * x4.z;
        acc[i][3] += wv[i] * x4.w;
      }
    }
  }
  __syncthreads();

  // epilogue: dt-rank rows -> LDS; B/C rows -> global
#pragma unroll
  for (int i = 0; i < 6; ++i) {
    int r = ty * 6 + i;
    int dir = r / 48, rr = r - dir * 48;
    float4 v = make_float4(acc[i][0], acc[i][1], acc[i][2], acc[i][3]);
    if (rr < 16) {
      *(float4*)&dtlds[(dir * 16 + rr) * 68 + tx * 4] = v;
    } else if (rr < 32) {
      *(float4*)(gB + (((size_t)dir * BN + b) * NS + (rr - 16)) * LL + l0 + tx * 4) = v;
    } else {
      *(float4*)(gC + (((size_t)dir * BN + b) * NS + (rr - 32)) * LL + l0 + tx * 4) = v;
    }
  }
  __syncthreads();

  // dt_proj + softplus: wave-uniform d per iteration, coalesced stores
  const int lt = tid & 63, dgrp = tid >> 6;
  for (int dir = 0; dir < 2; ++dir) {
    const float* dw = dir ? dtwB : dtw;
    const float* dl0 = &dtlds[dir * 16 * 68];
    for (int d = dgrp * 64; d < dgrp * 64 + 64; ++d) {
      float accv = dtb[d];
#pragma unroll
      for (int r = 0; r < 16; ++r) accv += dw[d * 16 + r] * dl0[r * 68 + lt];
      gdelta[(((size_t)dir * BN + b) * DD + d) * LL + l0 + lt] = softplus_f(accv);
    }
  }
}

// ---------------- K4: scan pass A — per-chunk q and P = exp(An*sum(dl)) ----------------
__global__ __launch_bounds__(256) void k4_scanA(
    const float* __restrict__ gdelta, const float* __restrict__ x,
    const float* __restrict__ gB,
    const float* __restrict__ Alog, const float* __restrict__ AlogB,
    float* __restrict__ Pbuf, float* __restrict__ qbuf) {
  __shared__ float sdl[16 * SP];
  __shared__ float sdx[16 * SP];
  __shared__ float sB[16 * SP];
  const int s = blockIdx.x;
  const int dbase = blockIdx.y * 16;
  const int dir = blockIdx.z >> 2, b = blockIdx.z & 3;
  const int t0 = s * CT;
  const int tid = threadIdx.x;

  for (int idx = tid; idx < 16 * 32; idx += 256) {
    int row = idx >> 5, q = idx & 31;
    float4 dl = *(const float4*)(gdelta + (((size_t)dir * BN + b) * DD + dbase + row) * LL + t0 + q * 4);
    float4 xv;
    if (dir == 0) {
      xv = *(const float4*)(x + ((size_t)b * DD + dbase + row) * LL + t0 + q * 4);
    } else {
      const float* xrow = x + ((size_t)b * DD + dbase + row) * LL;
      float4 t = *(const float4*)(xrow + (LL - 4 - t0 - q * 4));
      xv = make_float4(t.w, t.z, t.y, t.x);
    }
    *(float4*)&sdl[row * SP + q * 4] = dl;
    *(float4*)&sdx[row * SP + q * 4] =
        make_float4(dl.x * xv.x, dl.y * xv.y, dl.z * xv.z, dl.w * xv.w);
    *(float4*)&sB[row * SP + q * 4] =
        *(const float4*)(gB + (((size_t)dir * BN + b) * NS + row) * LL + t0 + q * 4);
  }
  __syncthreads();

  const int g = tid >> 4, n = tid & 15;
  const int d = dbase + g;
  const float An = -__expf((dir ? AlogB : Alog)[d * NS + n]);
  float h = 0.f, S = 0.f;
#pragma unroll 4
  for (int jb = 0; jb < CT; jb += 4) {
    float4 dl4 = *(float4*)&sdl[g * SP + jb];
    float4 dx4 = *(float4*)&sdx[g * SP + jb];
    float4 B4  = *(float4*)&sB[n * SP + jb];
    h = h * __expf(dl4.x * An) + dx4.x * B4.x;
    h = h * __expf(dl4.y * An) + dx4.y * B4.y;
    h = h * __expf(dl4.z * An) + dx4.z * B4.z;
    h = h * __expf(dl4.w * An) + dx4.w * B4.w;
    S += dl4.x + dl4.y + dl4.z + dl4.w;
  }
  const size_t pidx = ((((size_t)dir * BN + b) * DD + d) * NCH + s) * NS + n;
  Pbuf[pidx] = __expf(An * S);
  qbuf[pidx] = h;
}

// ---------------- K5: middle scan over chunks ----------------
__global__ __launch_bounds__(256) void k5_mid(
    const float* __restrict__ Pbuf, float* __restrict__ qbuf) {
  int id = blockIdx.x * 256 + threadIdx.x;
  int n = id & 15;
  int d = (id >> 4) & 255;
  int rb = id >> 12;
  size_t base = (((size_t)rb * DD + d) * NCH) * NS + n;
  float h = 0.f;
  for (int s = 0; s < NCH; ++s) {
    size_t idx = base + (size_t)s * NS;
    float Pv = Pbuf[idx];
    float qv = qbuf[idx];
    qbuf[idx] = h;
    h = h * Pv + qv;
  }
}

// ---------------- K6: scan pass C — replay with h0, LDS-transpose y reduction ----------------
__global__ __launch_bounds__(256) void k6_scanC(
    const float* __restrict__ gdelta, const float* __restrict__ x,
    const float* __restrict__ gB, const float* __restrict__ gC,
    const float* __restrict__ zb,
    const float* __restrict__ Alog, const float* __restrict__ AlogB,
    const float* __restrict__ Dvec, const float* __restrict__ DvecB,
    const float* __restrict__ hstart,
    float* __restrict__ y, float* __restrict__ yb) {
  __shared__ float sdl[16 * SP];
  __shared__ float sx[16 * SP];
  __shared__ float sB[16 * SP];
  __shared__ float sC[16 * SP];
  __shared__ float ylds[16 * 16 * 17];
  const int s = blockIdx.x;
  const int dbase = blockIdx.y * 16;
  const int dir = blockIdx.z >> 2, b = blockIdx.z & 3;
  const int t0 = s * CT;
  const int tid = threadIdx.x;

  for (int idx = tid; idx < 16 * 32; idx += 256) {
    int row = idx >> 5, q = idx & 31;
    *(float4*)&sdl[row * SP + q * 4] =
        *(const float4*)(gdelta + (((size_t)dir * BN + b) * DD + dbase + row) * LL + t0 + q * 4);
    float4 xv;
    if (dir == 0) {
      xv = *(const float4*)(x + ((size_t)b * DD + dbase + row) * LL + t0 + q * 4);
    } else {
      const float* xrow = x + ((size_t)b * DD + dbase + row) * LL;
      float4 t = *(const float4*)(xrow + (LL - 4 - t0 - q * 4));
      xv = make_float4(t.w, t.z, t.y, t.x);
    }
    *(float4*)&sx[row * SP + q * 4] = xv;
    *(float4*)&sB[row * SP + q * 4] =
        *(const float4*)(gB + (((size_t)dir * BN + b) * NS + row) * LL + t0 + q * 4);
    *(float4*)&sC[row * SP + q * 4] =
        *(const float4*)(gC + (((size_t)dir * BN + b) * NS + row) * LL + t0 + q * 4);
  }
  __syncthreads();

  const int g = tid >> 4, n = tid & 15;
  const int d = dbase + g;
  const float An = -__expf((dir ? AlogB : Alog)[d * NS + n]);
  const float Dd = (dir ? DvecB : Dvec)[d];
  const size_t pidx = ((((size_t)dir * BN + b) * DD + d) * NCH + s) * NS + n;
  float h = hstart[pidx];
  float* dst = (dir ? yb : y) + ((size_t)b * DD + d) * LL;
  const float* zrow = zb + ((size_t)b * DD + d) * LL;
  const int yrow = (g * 16 + n) * 17;

  for (int jb = 0; jb < CT; jb += 16) {
#pragma unroll
    for (int q = 0; q < 4; ++q) {
      int j4 = jb + q * 4;
      float4 dl4 = *(float4*)&sdl[g * SP + j4];
      float4 x4  = *(float4*)&sx[g * SP + j4];
      float4 B4  = *(float4*)&sB[n * SP + j4];
      float4 C4  = *(float4*)&sC[n * SP + j4];
      h = h * __expf(dl4.x * An) + (dl4.x * x4.x) * B4.x; ylds[yrow + q * 4 + 0] = h * C4.x;
      h = h * __expf(dl4.y * An) + (dl4.y * x4.y) * B4.y; ylds[yrow + q * 4 + 1] = h * C4.y;
      h = h * __expf(dl4.z * An) + (dl4.z * x4.z) * B4.z; ylds[yrow + q * 4 + 2] = h * C4.z;
      h = h * __expf(dl4.w * An) + (dl4.w * x4.w) * B4.w; ylds[yrow + q * 4 + 3] = h * C4.w;
    }
    float ysum = 0.f;
#pragma unroll
    for (int m = 0; m < 16; ++m) ysum += ylds[(g * 16 + m) * 17 + n];
    int t = jb + n;
    float xv = sx[g * SP + t];
    float zv = zrow[t0 + t];
    dst[t0 + t] = (ysum + Dd * xv) * silu_f(zv);
  }
}

// ---------------- K7: dual LayerNorm + double SiLU gate + flip-add ----------------
__global__ __launch_bounds__(256) void k7_final(
    const float* __restrict__ y, const float* __restrict__ yb,
    const float* __restrict__ zb,
    const float* __restrict__ lnw, const float* __restrict__ lnb,
    const float* __restrict__ ln1w, const float* __restrict__ ln1b,
    float* __restrict__ out) {
  __shared__ float sy[LL];
  __shared__ float syb[LL];
  __shared__ float rsum[4][4];
  const int row = blockIdx.x;
  const int tid = threadIdx.x;
  const size_t base = (size_t)row * LL;
  float s1y = 0.f, s2y = 0.f, s1b = 0.f, s2b = 0.f;
  for (int j = tid * 4; j < LL; j += 1024) {
    float4 v = *(const float4*)(y + base + j);
    *(float4*)&sy[j] = v;
    s1y += v.x + v.y + v.z + v.w;
    s2y += v.x * v.x + v.y * v.y + v.z * v.z + v.w * v.w;
    float4 w = *(const float4*)(yb + base + j);
    *(float4*)&syb[j] = w;
    s1b += w.x + w.y + w.z + w.w;
    s2b += w.x * w.x + w.y * w.y + w.z * w.z + w.w * w.w;
  }
#pragma unroll
  for (int m = 1; m < 64; m <<= 1) {
    s1y += __shfl_xor(s1y, m); s2y += __shfl_xor(s2y, m);
    s1b += __shfl_xor(s1b, m); s2b += __shfl_xor(s2b, m);
  }
  int wv = tid >> 6;
  if ((tid & 63) == 0) { rsum[wv][0] = s1y; rsum[wv][1] = s2y; rsum[wv][2] = s1b; rsum[wv][3] = s2b; }
  __syncthreads();
  float t1y = rsum[0][0] + rsum[1][0] + rsum[2][0] + rsum[3][0];
  float t2y = rsum[0][1] + rsum[1][1] + rsum[2][1] + rsum[3][1];
  float t1b = rsum[0][2] + rsum[1][2] + rsum[2][2] + rsum[3][2];
  float t2b = rsum[0][3] + rsum[1][3] + rsum[2][3] + rsum[3][3];
  const float inv = 1.f / (float)LL;
  float mY = t1y * inv; float vY = t2y * inv - mY * mY; float rY = rsqrtf(vY + 1e-5f);
  float mB = t1b * inv; float vB = t2b * inv - mB * mB; float rB = rsqrtf(vB + 1e-5f);
  for (int j = tid; j < LL; j += 256) {
    int jr = LL - 1 - j;
    float a  = (sy[j]  - mY) * rY * lnw[j]   + lnb[j];
    float g1 = silu_f(zb[base + j]);
    float bv = (syb[jr] - mB) * rB * ln1w[jr] + ln1b[jr];
    float g2 = silu_f(zb[base + jr]);
    out[base + j] = a * g1 + bv * g2;
  }
}

extern "C" void kernel_launch(void* const* d_in, const int* in_sizes, int n_in,
                              void* d_out, int out_size, void* d_ws, size_t ws_size,
                              hipStream_t stream) {
  const float* u     = (const float*)d_in[0];
  const float* inw   = (const float*)d_in[1];
  const float* cw    = (const float*)d_in[2];
  const float* cb    = (const float*)d_in[3];
  const float* xpw   = (const float*)d_in[4];
  const float* dtw   = (const float*)d_in[5];
  const float* dtb   = (const float*)d_in[6];
  const float* Alog  = (const float*)d_in[7];
  const float* Dv    = (const float*)d_in[8];
  const float* xpwB  = (const float*)d_in[9];
  const float* dtwB  = (const float*)d_in[10];
  const float* AlogB = (const float*)d_in[11];
  const float* DvB   = (const float*)d_in[12];
  const float* lnw   = (const float*)d_in[13];
  const float* lnb   = (const float*)d_in[14];
  const float* ln1w  = (const float*)d_in[15];
  const float* ln1b  = (const float*)d_in[16];
  float* out = (float*)d_out;

  float* ws = (float*)d_ws;
  const size_t SZ = (size_t)BN * DD * LL;        // 4,194,304 floats
  float* xpre   = ws;
  float* zb     = ws + SZ;
  float* xc     = ws + 2 * SZ;
  float* gdelta = ws + 3 * SZ;        // 2 dirs
  float* gB     = ws + 5 * SZ;
  float* gC     = gB + SZ / 8;
  float* Pbuf   = gC + SZ / 8;
  float* qbuf   = Pbuf + SZ / 4;      // becomes hstart after k5_mid
  float* ybuf   = xpre;               // alias: xpre dead after k3
  float* ybbuf  = qbuf + SZ / 4;

  k1_inproj<<<dim3(32, 4, 4), 256, 0, stream>>>(inw, u, xpre, zb);
  k3_proj<<<dim3(64, 4), 256, 0, stream>>>(xpre, cw, cb, xpw, dtw, dtb, xpwB, dtwB,
                                           gdelta, gB, gC, xc);
  k4_scanA<<<dim3(NCH, 16, 8), 256, 0, stream>>>(gdelta, xc, gB, Alog, AlogB, Pbuf, qbuf);
  k5_mid<<<128, 256, 0, stream>>>(Pbuf, qbuf);
  k6_scanC<<<dim3(NCH, 16, 8), 256, 0, stream>>>(gdelta, xc, gB, gC, zb, Alog, AlogB,
                                                 Dv, DvB, qbuf, ybuf, ybbuf);
  k7_final<<<1024, 256, 0, stream>>>(ybuf, ybbuf, zb, lnw, lnb, ln1w, ln1b, out);
}

// Round 4
// 354.601 us; speedup vs baseline: 1.1071x; 1.1071x over previous
//
#include <hip/hip_runtime.h>
#include <math.h>

#define BN 4
#define DD 256
#define LL 4096
#define NS 16
#define NCH 32   // scan chunks
#define CT 128   // chunk length (NCH*CT == LL)
#define SP 132   // CT + 4 pad

__device__ __forceinline__ float softplus_f(float v) {
  return v > 20.f ? v : log1pf(__expf(v));
}
__device__ __forceinline__ float silu_f(float v) {
  return v / (1.f + __expf(-v));
}

// ---------------- K1: xz = in_proj_w (512x256) @ U[b] (256x4096) ----------------
__global__ __launch_bounds__(256) void k1_inproj(
    const float* __restrict__ W, const float* __restrict__ U,
    float* __restrict__ xpre, float* __restrict__ zb) {
  __shared__ float Wt[16][128];  // [k][e]
  __shared__ float Ut[16][128];  // [k][l]
  const int l0 = blockIdx.x * 128;
  const int e0 = blockIdx.y * 128;
  const int b  = blockIdx.z;
  const int tid = threadIdx.x;
  const int tx = tid & 15, ty = tid >> 4;
  const float* Ub = U + (size_t)b * DD * LL;
  float acc[8][8];
#pragma unroll
  for (int i = 0; i < 8; ++i)
#pragma unroll
    for (int j = 0; j < 8; ++j) acc[i][j] = 0.f;

  for (int k0 = 0; k0 < DD; k0 += 16) {
#pragma unroll
    for (int i = 0; i < 2; ++i) {
      int idx = tid * 8 + i * 4;
      int e = idx >> 4, kk = idx & 15;
      float4 v = *(const float4*)(W + (size_t)(e0 + e) * DD + k0 + kk);
      Wt[kk + 0][e] = v.x; Wt[kk + 1][e] = v.y;
      Wt[kk + 2][e] = v.z; Wt[kk + 3][e] = v.w;
    }
#pragma unroll
    for (int i = 0; i < 2; ++i) {
      int idx = tid * 4 + i * 1024;
      int kk = idx >> 7, l = idx & 127;
      *(float4*)&Ut[kk][l] = *(const float4*)(Ub + (size_t)(k0 + kk) * LL + l0 + l);
    }
    __syncthreads();
#pragma unroll
    for (int kk = 0; kk < 16; ++kk) {
      float a[8], bb2[8];
#pragma unroll
      for (int i = 0; i < 4; ++i) { a[i] = Wt[kk][ty * 4 + i]; a[i + 4] = Wt[kk][64 + ty * 4 + i]; }
#pragma unroll
      for (int j = 0; j < 4; ++j) { bb2[j] = Ut[kk][tx * 4 + j]; bb2[j + 4] = Ut[kk][64 + tx * 4 + j]; }
#pragma unroll
      for (int i = 0; i < 8; ++i)
#pragma unroll
        for (int j = 0; j < 8; ++j) acc[i][j] += a[i] * bb2[j];
    }
    __syncthreads();
  }
#pragma unroll
  for (int i = 0; i < 8; ++i) {
    int e = e0 + ((i < 4) ? (ty * 4 + i) : (64 + ty * 4 + (i - 4)));
    float* dst = (e < DD) ? (xpre + ((size_t)b * DD + e) * LL)
                          : (zb   + ((size_t)b * DD + (e - DD)) * LL);
    float4 v0 = make_float4(acc[i][0], acc[i][1], acc[i][2], acc[i][3]);
    float4 v1 = make_float4(acc[i][4], acc[i][5], acc[i][6], acc[i][7]);
    *(float4*)(dst + l0 + tx * 4) = v0;
    *(float4*)(dst + l0 + 64 + tx * 4) = v1;
  }
}

// ---------------- K2: depthwise conv == 3-tap along d, weights per l ----------------
__global__ __launch_bounds__(256) void k2_conv(
    const float* __restrict__ xpre, const float* __restrict__ cw,
    const float* __restrict__ cb, float* __restrict__ xo) {
  const int bd = blockIdx.x;       // b*256 + d
  const int d = bd & 255;
  const size_t row = (size_t)bd * LL;
  const float* r1 = xpre + row;
  const bool has0 = d > 0, has2 = d < DD - 1;
  for (int j = threadIdx.x; j < LL; j += 256) {
    float w0 = cw[j * 9 + 3], w1 = cw[j * 9 + 4], w2 = cw[j * 9 + 5];
    float v = cb[j] + r1[j] * w1;
    if (has0) v += r1[j - LL] * w0;
    if (has2) v += r1[j + LL] * w2;
    xo[row + j] = v;
  }
}

// ---------------- K3: x_proj GEMM, scalar-pipe weights, no LDS / no barriers ----
// Thread = one column l. 12 of 48 rows per block (rows: 0-15 dt-rank, 16-31 B, 32-47 C).
__global__ __launch_bounds__(256) void k3_xproj(
    const float* __restrict__ xc,
    const float* __restrict__ xpw, const float* __restrict__ xpwB,
    float* __restrict__ dtr, float* __restrict__ gB, float* __restrict__ gC) {
  const int tid = threadIdx.x;
  const int l   = blockIdx.x * 256 + tid;
  const int b   = blockIdx.y;
  const int zz  = blockIdx.z;            // dir*4 + rgroup
  const int dir = zz >> 2, rg = zz & 3;
  const int rbase = rg * 12;
  const float* W = (dir ? xpwB : xpw) + (size_t)rbase * DD;   // 12 rows x 256
  const float* xcol = xc + (size_t)b * DD * LL + l;

  float acc[12];
#pragma unroll
  for (int i = 0; i < 12; ++i) acc[i] = 0.f;

#pragma unroll 8
  for (int d = 0; d < DD; ++d) {
    float xv = xcol[(size_t)d * LL];
#pragma unroll
    for (int i = 0; i < 12; ++i) acc[i] += W[i * DD + d] * xv;
  }

  const size_t ob = ((size_t)dir * BN + b);
#pragma unroll
  for (int i = 0; i < 12; ++i) {
    int r = rbase + i;
    if (r < 16)
      dtr[(ob * 16 + r) * LL + l] = acc[i];
    else if (r < 32)
      gB[(ob * NS + (r - 16)) * LL + l] = acc[i];
    else
      gC[(ob * NS + (r - 32)) * LL + l] = acc[i];
  }
}

// ---------------- K3b: dt_proj + softplus -> gdelta; dtr register-cached ----------
__global__ __launch_bounds__(256) void k3b_dtproj(
    const float* __restrict__ dtr,
    const float* __restrict__ dtw, const float* __restrict__ dtwB,
    const float* __restrict__ dtb,
    float* __restrict__ gdelta) {
  const int tid = threadIdx.x;
  const int l   = blockIdx.x * 256 + tid;
  const int b   = blockIdx.y & 3;
  const int dir = blockIdx.y >> 2;
  const int d0  = blockIdx.z * 64;
  const size_t ob = ((size_t)dir * BN + b);
  const float* dw = (dir ? dtwB : dtw);

  float tr[16];
#pragma unroll
  for (int r = 0; r < 16; ++r) tr[r] = dtr[(ob * 16 + r) * LL + l];

#pragma unroll 4
  for (int d = d0; d < d0 + 64; ++d) {
    float acc = dtb[d];
#pragma unroll
    for (int r = 0; r < 16; ++r) acc += dw[d * 16 + r] * tr[r];
    gdelta[(ob * DD + d) * LL + l] = softplus_f(acc);
  }
}

// ---------------- K4: scan pass A — per-chunk q and P = exp(An*sum(dl)) ----------------
__global__ __launch_bounds__(256) void k4_scanA(
    const float* __restrict__ gdelta, const float* __restrict__ x,
    const float* __restrict__ gB,
    const float* __restrict__ Alog, const float* __restrict__ AlogB,
    float* __restrict__ Pbuf, float* __restrict__ qbuf) {
  __shared__ float sdl[16 * SP];
  __shared__ float sdx[16 * SP];
  __shared__ float sB[16 * SP];
  const int s = blockIdx.x;
  const int dbase = blockIdx.y * 16;
  const int dir = blockIdx.z >> 2, b = blockIdx.z & 3;
  const int t0 = s * CT;
  const int tid = threadIdx.x;

  for (int idx = tid; idx < 16 * 32; idx += 256) {
    int row = idx >> 5, q = idx & 31;
    float4 dl = *(const float4*)(gdelta + (((size_t)dir * BN + b) * DD + dbase + row) * LL + t0 + q * 4);
    float4 xv;
    if (dir == 0) {
      xv = *(const float4*)(x + ((size_t)b * DD + dbase + row) * LL + t0 + q * 4);
    } else {
      const float* xrow = x + ((size_t)b * DD + dbase + row) * LL;
      float4 t = *(const float4*)(xrow + (LL - 4 - t0 - q * 4));
      xv = make_float4(t.w, t.z, t.y, t.x);
    }
    *(float4*)&sdl[row * SP + q * 4] = dl;
    *(float4*)&sdx[row * SP + q * 4] =
        make_float4(dl.x * xv.x, dl.y * xv.y, dl.z * xv.z, dl.w * xv.w);
    *(float4*)&sB[row * SP + q * 4] =
        *(const float4*)(gB + (((size_t)dir * BN + b) * NS + row) * LL + t0 + q * 4);
  }
  __syncthreads();

  const int g = tid >> 4, n = tid & 15;
  const int d = dbase + g;
  const float An = -__expf((dir ? AlogB : Alog)[d * NS + n]);
  float h = 0.f, S = 0.f;
#pragma unroll 4
  for (int jb = 0; jb < CT; jb += 4) {
    float4 dl4 = *(float4*)&sdl[g * SP + jb];
    float4 dx4 = *(float4*)&sdx[g * SP + jb];
    float4 B4  = *(float4*)&sB[n * SP + jb];
    h = h * __expf(dl4.x * An) + dx4.x * B4.x;
    h = h * __expf(dl4.y * An) + dx4.y * B4.y;
    h = h * __expf(dl4.z * An) + dx4.z * B4.z;
    h = h * __expf(dl4.w * An) + dx4.w * B4.w;
    S += dl4.x + dl4.y + dl4.z + dl4.w;
  }
  const size_t pidx = ((((size_t)dir * BN + b) * DD + d) * NCH + s) * NS + n;
  Pbuf[pidx] = __expf(An * S);
  qbuf[pidx] = h;
}

// ---------------- K5: middle scan over chunks ----------------
__global__ __launch_bounds__(256) void k5_mid(
    const float* __restrict__ Pbuf, float* __restrict__ qbuf) {
  int id = blockIdx.x * 256 + threadIdx.x;
  int n = id & 15;
  int d = (id >> 4) & 255;
  int rb = id >> 12;
  size_t base = (((size_t)rb * DD + d) * NCH) * NS + n;
  float h = 0.f;
  for (int s = 0; s < NCH; ++s) {
    size_t idx = base + (size_t)s * NS;
    float Pv = Pbuf[idx];
    float qv = qbuf[idx];
    qbuf[idx] = h;
    h = h * Pv + qv;
  }
}

// ---------------- K6: scan pass C — replay with h0, LDS-transpose y reduction ----------------
__global__ __launch_bounds__(256) void k6_scanC(
    const float* __restrict__ gdelta, const float* __restrict__ x,
    const float* __restrict__ gB, const float* __restrict__ gC,
    const float* __restrict__ zb,
    const float* __restrict__ Alog, const float* __restrict__ AlogB,
    const float* __restrict__ Dvec, const float* __restrict__ DvecB,
    const float* __restrict__ hstart,
    float* __restrict__ y, float* __restrict__ yb) {
  __shared__ float sdl[16 * SP];
  __shared__ float sx[16 * SP];
  __shared__ float sB[16 * SP];
  __shared__ float sC[16 * SP];
  __shared__ float ylds[16 * 16 * 17];
  const int s = blockIdx.x;
  const int dbase = blockIdx.y * 16;
  const int dir = blockIdx.z >> 2, b = blockIdx.z & 3;
  const int t0 = s * CT;
  const int tid = threadIdx.x;

  for (int idx = tid; idx < 16 * 32; idx += 256) {
    int row = idx >> 5, q = idx & 31;
    *(float4*)&sdl[row * SP + q * 4] =
        *(const float4*)(gdelta + (((size_t)dir * BN + b) * DD + dbase + row) * LL + t0 + q * 4);
    float4 xv;
    if (dir == 0) {
      xv = *(const float4*)(x + ((size_t)b * DD + dbase + row) * LL + t0 + q * 4);
    } else {
      const float* xrow = x + ((size_t)b * DD + dbase + row) * LL;
      float4 t = *(const float4*)(xrow + (LL - 4 - t0 - q * 4));
      xv = make_float4(t.w, t.z, t.y, t.x);
    }
    *(float4*)&sx[row * SP + q * 4] = xv;
    *(float4*)&sB[row * SP + q * 4] =
        *(const float4*)(gB + (((size_t)dir * BN + b) * NS + row) * LL + t0 + q * 4);
    *(float4*)&sC[row * SP + q * 4] =
        *(const float4*)(gC + (((size_t)dir * BN + b) * NS + row) * LL + t0 + q * 4);
  }
  __syncthreads();

  const int g = tid >> 4, n = tid & 15;
  const int d = dbase + g;
  const float An = -__expf((dir ? AlogB : Alog)[d * NS + n]);
  const float Dd = (dir ? DvecB : Dvec)[d];
  const size_t pidx = ((((size_t)dir * BN + b) * DD + d) * NCH + s) * NS + n;
  float h = hstart[pidx];
  float* dst = (dir ? yb : y) + ((size_t)b * DD + d) * LL;
  const float* zrow = zb + ((size_t)b * DD + d) * LL;
  const int yrow = (g * 16 + n) * 17;

  for (int jb = 0; jb < CT; jb += 16) {
#pragma unroll
    for (int q = 0; q < 4; ++q) {
      int j4 = jb + q * 4;
      float4 dl4 = *(float4*)&sdl[g * SP + j4];
      float4 x4  = *(float4*)&sx[g * SP + j4];
      float4 B4  = *(float4*)&sB[n * SP + j4];
      float4 C4  = *(float4*)&sC[n * SP + j4];
      h = h * __expf(dl4.x * An) + (dl4.x * x4.x) * B4.x; ylds[yrow + q * 4 + 0] = h * C4.x;
      h = h * __expf(dl4.y * An) + (dl4.y * x4.y) * B4.y; ylds[yrow + q * 4 + 1] = h * C4.y;
      h = h * __expf(dl4.z * An) + (dl4.z * x4.z) * B4.z; ylds[yrow + q * 4 + 2] = h * C4.z;
      h = h * __expf(dl4.w * An) + (dl4.w * x4.w) * B4.w; ylds[yrow + q * 4 + 3] = h * C4.w;
    }
    float ysum = 0.f;
#pragma unroll
    for (int m = 0; m < 16; ++m) ysum += ylds[(g * 16 + m) * 17 + n];
    int t = jb + n;
    float xv = sx[g * SP + t];
    float zv = zrow[t0 + t];
    dst[t0 + t] = (ysum + Dd * xv) * silu_f(zv);
  }
}

// ---------------- K7: dual LayerNorm + double SiLU gate + flip-add ----------------
__global__ __launch_bounds__(256) void k7_final(
    const float* __restrict__ y, const float* __restrict__ yb,
    const float* __restrict__ zb,
    const float* __restrict__ lnw, const float* __restrict__ lnb,
    const float* __restrict__ ln1w, const float* __restrict__ ln1b,
    float* __restrict__ out) {
  __shared__ float sy[LL];
  __shared__ float syb[LL];
  __shared__ float rsum[4][4];
  const int row = blockIdx.x;
  const int tid = threadIdx.x;
  const size_t base = (size_t)row * LL;
  float s1y = 0.f, s2y = 0.f, s1b = 0.f, s2b = 0.f;
  for (int j = tid * 4; j < LL; j += 1024) {
    float4 v = *(const float4*)(y + base + j);
    *(float4*)&sy[j] = v;
    s1y += v.x + v.y + v.z + v.w;
    s2y += v.x * v.x + v.y * v.y + v.z * v.z + v.w * v.w;
    float4 w = *(const float4*)(yb + base + j);
    *(float4*)&syb[j] = w;
    s1b += w.x + w.y + w.z + w.w;
    s2b += w.x * w.x + w.y * w.y + w.z * w.z + w.w * w.w;
  }
#pragma unroll
  for (int m = 1; m < 64; m <<= 1) {
    s1y += __shfl_xor(s1y, m); s2y += __shfl_xor(s2y, m);
    s1b += __shfl_xor(s1b, m); s2b += __shfl_xor(s2b, m);
  }
  int wv = tid >> 6;
  if ((tid & 63) == 0) { rsum[wv][0] = s1y; rsum[wv][1] = s2y; rsum[wv][2] = s1b; rsum[wv][3] = s2b; }
  __syncthreads();
  float t1y = rsum[0][0] + rsum[1][0] + rsum[2][0] + rsum[3][0];
  float t2y = rsum[0][1] + rsum[1][1] + rsum[2][1] + rsum[3][1];
  float t1b = rsum[0][2] + rsum[1][2] + rsum[2][2] + rsum[3][2];
  float t2b = rsum[0][3] + rsum[1][3] + rsum[2][3] + rsum[3][3];
  const float inv = 1.f / (float)LL;
  float mY = t1y * inv; float vY = t2y * inv - mY * mY; float rY = rsqrtf(vY + 1e-5f);
  float mB = t1b * inv; float vB = t2b * inv - mB * mB; float rB = rsqrtf(vB + 1e-5f);
  for (int j = tid; j < LL; j += 256) {
    int jr = LL - 1 - j;
    float a  = (sy[j]  - mY) * rY * lnw[j]   + lnb[j];
    float g1 = silu_f(zb[base + j]);
    float bv = (syb[jr] - mB) * rB * ln1w[jr] + ln1b[jr];
    float g2 = silu_f(zb[base + jr]);
    out[base + j] = a * g1 + bv * g2;
  }
}

extern "C" void kernel_launch(void* const* d_in, const int* in_sizes, int n_in,
                              void* d_out, int out_size, void* d_ws, size_t ws_size,
                              hipStream_t stream) {
  const float* u     = (const float*)d_in[0];
  const float* inw   = (const float*)d_in[1];
  const float* cw    = (const float*)d_in[2];
  const float* cb    = (const float*)d_in[3];
  const float* xpw   = (const float*)d_in[4];
  const float* dtw   = (const float*)d_in[5];
  const float* dtb   = (const float*)d_in[6];
  const float* Alog  = (const float*)d_in[7];
  const float* Dv    = (const float*)d_in[8];
  const float* xpwB  = (const float*)d_in[9];
  const float* dtwB  = (const float*)d_in[10];
  const float* AlogB = (const float*)d_in[11];
  const float* DvB   = (const float*)d_in[12];
  const float* lnw   = (const float*)d_in[13];
  const float* lnb   = (const float*)d_in[14];
  const float* ln1w  = (const float*)d_in[15];
  const float* ln1b  = (const float*)d_in[16];
  float* out = (float*)d_out;

  float* ws = (float*)d_ws;
  const size_t SZ = (size_t)BN * DD * LL;        // 4,194,304 floats
  float* xpre   = ws;
  float* zb     = ws + SZ;
  float* xc     = ws + 2 * SZ;
  float* gdelta = ws + 3 * SZ;        // 2 dirs
  float* gB     = ws + 5 * SZ;
  float* gC     = gB + SZ / 8;
  float* Pbuf   = gC + SZ / 8;
  float* qbuf   = Pbuf + SZ / 4;      // becomes hstart after k5_mid
  float* ybbuf  = qbuf + SZ / 4;
  float* ybuf   = xpre;               // alias: xpre dead after k2
  float* dtr    = ybbuf;              // alias: dtr (SZ/8) dead before k6 writes ybbuf

  k1_inproj<<<dim3(32, 4, 4), 256, 0, stream>>>(inw, u, xpre, zb);
  k2_conv<<<1024, 256, 0, stream>>>(xpre, cw, cb, xc);
  k3_xproj<<<dim3(16, 4, 8), 256, 0, stream>>>(xc, xpw, xpwB, dtr, gB, gC);
  k3b_dtproj<<<dim3(16, 8, 4), 256, 0, stream>>>(dtr, dtw, dtwB, dtb, gdelta);
  k4_scanA<<<dim3(NCH, 16, 8), 256, 0, stream>>>(gdelta, xc, gB, Alog, AlogB, Pbuf, qbuf);
  k5_mid<<<128, 256, 0, stream>>>(Pbuf, qbuf);
  k6_scanC<<<dim3(NCH, 16, 8), 256, 0, stream>>>(gdelta, xc, gB, gC, zb, Alog, AlogB,
                                                 Dv, DvB, qbuf, ybuf, ybbuf);
  k7_final<<<1024, 256, 0, stream>>>(ybuf, ybbuf, zb, lnw, lnb, ln1w, ln1b, out);
}

// Round 5
// 334.439 us; speedup vs baseline: 1.1738x; 1.0603x over previous
//
#include <hip/hip_runtime.h>
#include <math.h>

#define BN 4
#define DD 256
#define LL 4096
#define NS 16
#define NCH 32   // scan chunks
#define CT 128   // chunk length (NCH*CT == LL)
#define SP 132   // CT + 4 pad

typedef __bf16 bf16x8 __attribute__((ext_vector_type(8)));
typedef float f32x4 __attribute__((ext_vector_type(4)));

__device__ __forceinline__ float softplus_f(float v) {
  return v > 20.f ? v : log1pf(__expf(v));
}
__device__ __forceinline__ float silu_f(float v) {
  return v / (1.f + __expf(-v));
}
__device__ __forceinline__ unsigned short f2bf(float x) {
  __bf16 h = (__bf16)x;
  return __builtin_bit_cast(unsigned short, h);
}

// ---------------- K0: u -> ubfT [b][l][d] bf16 (transpose), W -> WT bf16 ----------------
__global__ __launch_bounds__(256) void k0_pre(
    const float* __restrict__ u, const float* __restrict__ W,
    unsigned short* __restrict__ ubfT, unsigned short* __restrict__ WT) {
  const int tid = threadIdx.x;
  if (blockIdx.z == 4) {
    // W convert: 512x256 = 131072 elems over 256 blocks
    int blk = blockIdx.y * 64 + blockIdx.x;
    int g = blk * 256 + tid;
    float2 v = *(const float2*)(W + (size_t)g * 2);
    WT[g * 2]     = f2bf(v.x);
    WT[g * 2 + 1] = f2bf(v.y);
    return;
  }
  __shared__ float slds[64 * 65];
  const int l0 = blockIdx.x * 64;
  const int d0 = blockIdx.y * 64;
  const int b  = blockIdx.z;
  const int ty = tid >> 6, tx = tid & 63;
#pragma unroll
  for (int i = 0; i < 16; ++i) {
    int dloc = ty * 16 + i;
    slds[dloc * 65 + tx] = u[((size_t)b * DD + d0 + dloc) * LL + l0 + tx];
  }
  __syncthreads();
#pragma unroll
  for (int i = 0; i < 16; ++i) {
    int lloc = ty * 16 + i;
    ubfT[((size_t)b * LL + l0 + lloc) * DD + d0 + tx] = f2bf(slds[tx * 65 + lloc]);
  }
}

// ---------------- K1: MFMA bf16 GEMM: xz[e][l] = W[e][d] * u[d][l] ----------------
// Block: 128 e x 64 l; 4 waves, wave w covers e-rows [w*32, w*32+32).
__global__ __launch_bounds__(256) void k1_mfma(
    const unsigned short* __restrict__ WT, const unsigned short* __restrict__ ubfT,
    float* __restrict__ xpre, float* __restrict__ zb) {
  __shared__ unsigned short Alds[128 * 40];  // [e][k], row stride 40 (80B)
  __shared__ unsigned short Blds[64 * 40];   // [l][k]
  const int l0 = blockIdx.x * 64;
  const int e0 = blockIdx.y * 128;
  const int b  = blockIdx.z;
  const int tid = threadIdx.x;
  const int lane = tid & 63, w = tid >> 6;
  const int m16 = lane & 15, quad = lane >> 4;

  f32x4 acc[2][4];
#pragma unroll
  for (int i = 0; i < 2; ++i)
#pragma unroll
    for (int j = 0; j < 4; ++j) acc[i][j] = (f32x4){0.f, 0.f, 0.f, 0.f};

  const unsigned short* Ub = ubfT + (size_t)b * LL * DD;

  for (int k0 = 0; k0 < DD; k0 += 32) {
    if (k0) __syncthreads();
    // stage A: 128 rows x 4 quads of 16B
#pragma unroll
    for (int j = 0; j < 2; ++j) {
      int flat = tid + j * 256;
      int row = flat >> 2, q = flat & 3;
      *(uint4*)&Alds[row * 40 + q * 8] =
          *(const uint4*)(WT + (size_t)(e0 + row) * DD + k0 + q * 8);
    }
    // stage B: 64 rows x 4 quads
    {
      int row = tid >> 2, q = tid & 3;
      *(uint4*)&Blds[row * 40 + q * 8] =
          *(const uint4*)(Ub + (size_t)(l0 + row) * DD + k0 + q * 8);
    }
    __syncthreads();
    bf16x8 afr[2], bfr[4];
#pragma unroll
    for (int te = 0; te < 2; ++te)
      afr[te] = *(const bf16x8*)&Alds[(w * 32 + te * 16 + m16) * 40 + quad * 8];
#pragma unroll
    for (int tl = 0; tl < 4; ++tl)
      bfr[tl] = *(const bf16x8*)&Blds[(tl * 16 + m16) * 40 + quad * 8];
#pragma unroll
    for (int te = 0; te < 2; ++te)
#pragma unroll
      for (int tl = 0; tl < 4; ++tl)
        acc[te][tl] = __builtin_amdgcn_mfma_f32_16x16x32_bf16(afr[te], bfr[tl], acc[te][tl], 0, 0, 0);
  }

  // epilogue: row = quad*4 + r (e), col = m16 (l)
#pragma unroll
  for (int te = 0; te < 2; ++te) {
#pragma unroll
    for (int tl = 0; tl < 4; ++tl) {
      int col = l0 + tl * 16 + m16;
#pragma unroll
      for (int r = 0; r < 4; ++r) {
        int e = e0 + w * 32 + te * 16 + quad * 4 + r;
        float v = acc[te][tl][r];
        if (e < DD) xpre[((size_t)b * DD + e) * LL + col] = v;
        else        zb[((size_t)b * DD + (e - DD)) * LL + col] = v;
      }
    }
  }
}

// ---------------- K2: depthwise conv == 3-tap along d, weights per l ----------------
__global__ __launch_bounds__(256) void k2_conv(
    const float* __restrict__ xpre, const float* __restrict__ cw,
    const float* __restrict__ cb, float* __restrict__ xo) {
  const int bd = blockIdx.x;       // b*256 + d
  const int d = bd & 255;
  const size_t row = (size_t)bd * LL;
  const float* r1 = xpre + row;
  const bool has0 = d > 0, has2 = d < DD - 1;
  for (int j = threadIdx.x; j < LL; j += 256) {
    float w0 = cw[j * 9 + 3], w1 = cw[j * 9 + 4], w2 = cw[j * 9 + 5];
    float v = cb[j] + r1[j] * w1;
    if (has0) v += r1[j - LL] * w0;
    if (has2) v += r1[j + LL] * w2;
    xo[row + j] = v;
  }
}

// ---------------- K3: x_proj GEMM, scalar-pipe weights, no LDS / no barriers ----
__global__ __launch_bounds__(256) void k3_xproj(
    const float* __restrict__ xc,
    const float* __restrict__ xpw, const float* __restrict__ xpwB,
    float* __restrict__ dtr, float* __restrict__ gB, float* __restrict__ gC) {
  const int tid = threadIdx.x;
  const int l   = blockIdx.x * 256 + tid;
  const int b   = blockIdx.y;
  const int zz  = blockIdx.z;            // dir*4 + rgroup
  const int dir = zz >> 2, rg = zz & 3;
  const int rbase = rg * 12;
  const float* W = (dir ? xpwB : xpw) + (size_t)rbase * DD;   // 12 rows x 256
  const float* xcol = xc + (size_t)b * DD * LL + l;

  float acc[12];
#pragma unroll
  for (int i = 0; i < 12; ++i) acc[i] = 0.f;

#pragma unroll 8
  for (int d = 0; d < DD; ++d) {
    float xv = xcol[(size_t)d * LL];
#pragma unroll
    for (int i = 0; i < 12; ++i) acc[i] += W[i * DD + d] * xv;
  }

  const size_t ob = ((size_t)dir * BN + b);
#pragma unroll
  for (int i = 0; i < 12; ++i) {
    int r = rbase + i;
    if (r < 16)
      dtr[(ob * 16 + r) * LL + l] = acc[i];
    else if (r < 32)
      gB[(ob * NS + (r - 16)) * LL + l] = acc[i];
    else
      gC[(ob * NS + (r - 32)) * LL + l] = acc[i];
  }
}

// ---------------- K3b: dt_proj + softplus -> gdelta; dtr register-cached ----------
__global__ __launch_bounds__(256) void k3b_dtproj(
    const float* __restrict__ dtr,
    const float* __restrict__ dtw, const float* __restrict__ dtwB,
    const float* __restrict__ dtb,
    float* __restrict__ gdelta) {
  const int tid = threadIdx.x;
  const int l   = blockIdx.x * 256 + tid;
  const int b   = blockIdx.y & 3;
  const int dir = blockIdx.y >> 2;
  const int d0  = blockIdx.z * 64;
  const size_t ob = ((size_t)dir * BN + b);
  const float* dw = (dir ? dtwB : dtw);

  float tr[16];
#pragma unroll
  for (int r = 0; r < 16; ++r) tr[r] = dtr[(ob * 16 + r) * LL + l];

#pragma unroll 4
  for (int d = d0; d < d0 + 64; ++d) {
    float acc = dtb[d];
#pragma unroll
    for (int r = 0; r < 16; ++r) acc += dw[d * 16 + r] * tr[r];
    gdelta[(ob * DD + d) * LL + l] = softplus_f(acc);
  }
}

// ---------------- K4: scan pass A — B in LDS; delta/x direct global (broadcast) ----
__global__ __launch_bounds__(256) void k4_scanA(
    const float* __restrict__ gdelta, const float* __restrict__ x,
    const float* __restrict__ gB,
    const float* __restrict__ Alog, const float* __restrict__ AlogB,
    float* __restrict__ Pbuf, float* __restrict__ qbuf) {
  __shared__ float sB[16 * SP];
  const int s = blockIdx.x;
  const int dbase = blockIdx.y * 16;
  const int dir = blockIdx.z >> 2, b = blockIdx.z & 3;
  const int t0 = s * CT;
  const int tid = threadIdx.x;

  for (int idx = tid; idx < 16 * 32; idx += 256) {
    int row = idx >> 5, q = idx & 31;
    *(float4*)&sB[row * SP + q * 4] =
        *(const float4*)(gB + (((size_t)dir * BN + b) * NS + row) * LL + t0 + q * 4);
  }
  __syncthreads();

  const int g = tid >> 4, n = tid & 15;
  const int d = dbase + g;
  const float An = -__expf((dir ? AlogB : Alog)[d * NS + n]);
  const float* dlrow = gdelta + (((size_t)dir * BN + b) * DD + d) * LL + t0;
  const float* xrow  = x + ((size_t)b * DD + d) * LL;
  float h = 0.f, S = 0.f;
#pragma unroll 8
  for (int jb = 0; jb < CT; jb += 4) {
    float4 dl4 = *(const float4*)(dlrow + jb);
    float4 x4;
    if (dir == 0) {
      x4 = *(const float4*)(xrow + t0 + jb);
    } else {
      float4 t = *(const float4*)(xrow + LL - 4 - t0 - jb);
      x4 = make_float4(t.w, t.z, t.y, t.x);
    }
    float4 B4 = *(float4*)&sB[n * SP + jb];
    h = h * __expf(dl4.x * An) + dl4.x * x4.x * B4.x;
    h = h * __expf(dl4.y * An) + dl4.y * x4.y * B4.y;
    h = h * __expf(dl4.z * An) + dl4.z * x4.z * B4.z;
    h = h * __expf(dl4.w * An) + dl4.w * x4.w * B4.w;
    S += dl4.x + dl4.y + dl4.z + dl4.w;
  }
  const size_t pidx = ((((size_t)dir * BN + b) * DD + d) * NCH + s) * NS + n;
  Pbuf[pidx] = __expf(An * S);
  qbuf[pidx] = h;
}

// ---------------- K5: middle scan over chunks ----------------
__global__ __launch_bounds__(256) void k5_mid(
    const float* __restrict__ Pbuf, float* __restrict__ qbuf) {
  int id = blockIdx.x * 256 + threadIdx.x;
  int n = id & 15;
  int d = (id >> 4) & 255;
  int rb = id >> 12;
  size_t base = (((size_t)rb * DD + d) * NCH) * NS + n;
  float h = 0.f;
  for (int s = 0; s < NCH; ++s) {
    size_t idx = base + (size_t)s * NS;
    float Pv = Pbuf[idx];
    float qv = qbuf[idx];
    qbuf[idx] = h;
    h = h * Pv + qv;
  }
}

// ---------------- K6: scan pass C — B/C in LDS; delta/x direct global ----------
__global__ __launch_bounds__(256) void k6_scanC(
    const float* __restrict__ gdelta, const float* __restrict__ x,
    const float* __restrict__ gB, const float* __restrict__ gC,
    const float* __restrict__ zb,
    const float* __restrict__ Alog, const float* __restrict__ AlogB,
    const float* __restrict__ Dvec, const float* __restrict__ DvecB,
    const float* __restrict__ hstart,
    float* __restrict__ y, float* __restrict__ yb) {
  __shared__ float sB[16 * SP];
  __shared__ float sC[16 * SP];
  __shared__ float ylds[16 * 16 * 17];
  const int s = blockIdx.x;
  const int dbase = blockIdx.y * 16;
  const int dir = blockIdx.z >> 2, b = blockIdx.z & 3;
  const int t0 = s * CT;
  const int tid = threadIdx.x;

  for (int idx = tid; idx < 16 * 32; idx += 256) {
    int row = idx >> 5, q = idx & 31;
    *(float4*)&sB[row * SP + q * 4] =
        *(const float4*)(gB + (((size_t)dir * BN + b) * NS + row) * LL + t0 + q * 4);
    *(float4*)&sC[row * SP + q * 4] =
        *(const float4*)(gC + (((size_t)dir * BN + b) * NS + row) * LL + t0 + q * 4);
  }
  __syncthreads();

  const int g = tid >> 4, n = tid & 15;
  const int d = dbase + g;
  const float An = -__expf((dir ? AlogB : Alog)[d * NS + n]);
  const float Dd = (dir ? DvecB : Dvec)[d];
  const size_t pidx = ((((size_t)dir * BN + b) * DD + d) * NCH + s) * NS + n;
  float h = hstart[pidx];
  float* dst = (dir ? yb : y) + ((size_t)b * DD + d) * LL;
  const float* dlrow = gdelta + (((size_t)dir * BN + b) * DD + d) * LL + t0;
  const float* xrow  = x + ((size_t)b * DD + d) * LL;
  const float* zrow  = zb + ((size_t)b * DD + d) * LL;
  const int yrow = (g * 16 + n) * 17;

  for (int jb = 0; jb < CT; jb += 16) {
#pragma unroll
    for (int q = 0; q < 4; ++q) {
      int j4 = jb + q * 4;
      float4 dl4 = *(const float4*)(dlrow + j4);
      float4 x4;
      if (dir == 0) {
        x4 = *(const float4*)(xrow + t0 + j4);
      } else {
        float4 t = *(const float4*)(xrow + LL - 4 - t0 - j4);
        x4 = make_float4(t.w, t.z, t.y, t.x);
      }
      float4 B4 = *(float4*)&sB[n * SP + j4];
      float4 C4 = *(float4*)&sC[n * SP + j4];
      h = h * __expf(dl4.x * An) + (dl4.x * x4.x) * B4.x; ylds[yrow + q * 4 + 0] = h * C4.x;
      h = h * __expf(dl4.y * An) + (dl4.y * x4.y) * B4.y; ylds[yrow + q * 4 + 1] = h * C4.y;
      h = h * __expf(dl4.z * An) + (dl4.z * x4.z) * B4.z; ylds[yrow + q * 4 + 2] = h * C4.z;
      h = h * __expf(dl4.w * An) + (dl4.w * x4.w) * B4.w; ylds[yrow + q * 4 + 3] = h * C4.w;
    }
    float ysum = 0.f;
#pragma unroll
    for (int m = 0; m < 16; ++m) ysum += ylds[(g * 16 + m) * 17 + n];
    int t = jb + n;
    float xv = (dir == 0) ? xrow[t0 + t] : xrow[LL - 1 - (t0 + t)];
    float zv = zrow[t0 + t];
    dst[t0 + t] = (ysum + Dd * xv) * silu_f(zv);
  }
}

// ---------------- K7: dual LayerNorm + double SiLU gate + flip-add ----------------
__global__ __launch_bounds__(256) void k7_final(
    const float* __restrict__ y, const float* __restrict__ yb,
    const float* __restrict__ zb,
    const float* __restrict__ lnw, const float* __restrict__ lnb,
    const float* __restrict__ ln1w, const float* __restrict__ ln1b,
    float* __restrict__ out) {
  __shared__ float sy[LL];
  __shared__ float syb[LL];
  __shared__ float rsum[4][4];
  const int row = blockIdx.x;
  const int tid = threadIdx.x;
  const size_t base = (size_t)row * LL;
  float s1y = 0.f, s2y = 0.f, s1b = 0.f, s2b = 0.f;
  for (int j = tid * 4; j < LL; j += 1024) {
    float4 v = *(const float4*)(y + base + j);
    *(float4*)&sy[j] = v;
    s1y += v.x + v.y + v.z + v.w;
    s2y += v.x * v.x + v.y * v.y + v.z * v.z + v.w * v.w;
    float4 w = *(const float4*)(yb + base + j);
    *(float4*)&syb[j] = w;
    s1b += w.x + w.y + w.z + w.w;
    s2b += w.x * w.x + w.y * w.y + w.z * w.z + w.w * w.w;
  }
#pragma unroll
  for (int m = 1; m < 64; m <<= 1) {
    s1y += __shfl_xor(s1y, m); s2y += __shfl_xor(s2y, m);
    s1b += __shfl_xor(s1b, m); s2b += __shfl_xor(s2b, m);
  }
  int wv = tid >> 6;
  if ((tid & 63) == 0) { rsum[wv][0] = s1y; rsum[wv][1] = s2y; rsum[wv][2] = s1b; rsum[wv][3] = s2b; }
  __syncthreads();
  float t1y = rsum[0][0] + rsum[1][0] + rsum[2][0] + rsum[3][0];
  float t2y = rsum[0][1] + rsum[1][1] + rsum[2][1] + rsum[3][1];
  float t1b = rsum[0][2] + rsum[1][2] + rsum[2][2] + rsum[3][2];
  float t2b = rsum[0][3] + rsum[1][3] + rsum[2][3] + rsum[3][3];
  const float inv = 1.f / (float)LL;
  float mY = t1y * inv; float vY = t2y * inv - mY * mY; float rY = rsqrtf(vY + 1e-5f);
  float mB = t1b * inv; float vB = t2b * inv - mB * mB; float rB = rsqrtf(vB + 1e-5f);
  for (int j = tid; j < LL; j += 256) {
    int jr = LL - 1 - j;
    float a  = (sy[j]  - mY) * rY * lnw[j]   + lnb[j];
    float g1 = silu_f(zb[base + j]);
    float bv = (syb[jr] - mB) * rB * ln1w[jr] + ln1b[jr];
    float g2 = silu_f(zb[base + jr]);
    out[base + j] = a * g1 + bv * g2;
  }
}

extern "C" void kernel_launch(void* const* d_in, const int* in_sizes, int n_in,
                              void* d_out, int out_size, void* d_ws, size_t ws_size,
                              hipStream_t stream) {
  const float* u     = (const float*)d_in[0];
  const float* inw   = (const float*)d_in[1];
  const float* cw    = (const float*)d_in[2];
  const float* cb    = (const float*)d_in[3];
  const float* xpw   = (const float*)d_in[4];
  const float* dtw   = (const float*)d_in[5];
  const float* dtb   = (const float*)d_in[6];
  const float* Alog  = (const float*)d_in[7];
  const float* Dv    = (const float*)d_in[8];
  const float* xpwB  = (const float*)d_in[9];
  const float* dtwB  = (const float*)d_in[10];
  const float* AlogB = (const float*)d_in[11];
  const float* DvB   = (const float*)d_in[12];
  const float* lnw   = (const float*)d_in[13];
  const float* lnb   = (const float*)d_in[14];
  const float* ln1w  = (const float*)d_in[15];
  const float* ln1b  = (const float*)d_in[16];
  float* out = (float*)d_out;

  float* ws = (float*)d_ws;
  const size_t SZ = (size_t)BN * DD * LL;        // 4,194,304 floats
  float* xpre   = ws;
  float* zb     = ws + SZ;
  float* xc     = ws + 2 * SZ;
  float* gdelta = ws + 3 * SZ;        // 2 dirs
  float* gB     = ws + 5 * SZ;
  float* gC     = gB + SZ / 8;
  float* Pbuf   = gC + SZ / 8;
  float* qbuf   = Pbuf + SZ / 4;      // becomes hstart after k5_mid
  float* ybbuf  = qbuf + SZ / 4;
  float* ybuf   = xpre;               // alias: xpre dead after k2
  float* dtr    = ybbuf;              // alias: dtr dead before k6 writes ybbuf
  // bf16 staging aliases inside the gdelta region (dead until k3b writes it):
  unsigned short* ubfT = (unsigned short*)(ws + 3 * SZ);           // SZ/2 floats
  unsigned short* WT   = (unsigned short*)(ws + 3 * SZ + SZ / 2);  // tiny

  k0_pre<<<dim3(64, 4, 5), 256, 0, stream>>>(u, inw, ubfT, WT);
  k1_mfma<<<dim3(64, 4, 4), 256, 0, stream>>>(WT, ubfT, xpre, zb);
  k2_conv<<<1024, 256, 0, stream>>>(xpre, cw, cb, xc);
  k3_xproj<<<dim3(16, 4, 8), 256, 0, stream>>>(xc, xpw, xpwB, dtr, gB, gC);
  k3b_dtproj<<<dim3(16, 8, 4), 256, 0, stream>>>(dtr, dtw, dtwB, dtb, gdelta);
  k4_scanA<<<dim3(NCH, 16, 8), 256, 0, stream>>>(gdelta, xc, gB, Alog, AlogB, Pbuf, qbuf);
  k5_mid<<<128, 256, 0, stream>>>(Pbuf, qbuf);
  k6_scanC<<<dim3(NCH, 16, 8), 256, 0, stream>>>(gdelta, xc, gB, gC, zb, Alog, AlogB,
                                                 Dv, DvB, qbuf, ybuf, ybbuf);
  k7_final<<<1024, 256, 0, stream>>>(ybuf, ybbuf, zb, lnw, lnb, ln1w, ln1b, out);
}